// Round 10
// baseline (50.199 us; speedup 1.0000x reference)
//
#include <hip/hip_runtime.h>

#define WSZ    64
#define BLOCK  256
#define STRIDE 20            // dwords/row: 16 data + 4 pad; (20*l)%32 = 4*(5l%8) -> each
                             // 8 consecutive lanes cover all 8 four-bank groups (b128-clean)
#define INV2PI 0.15915494309189535f   // v_sin/v_cos take revolutions

// Constant-address-space view: uniform compile-time indices off AS(4) lower to
// s_load through the scalar cache (coefs cost zero VALU/VMEM/LDS in hot loop).
typedef const __attribute__((address_space(4))) float cfloat;

// Writer: fold Rz(th1)*Ry(th0) into the 8-NZ Bloch 3x3 per step, into d_ws.
// Layout per step t: [m00 m01 m02 m10 m11 m12 m20 m22] (32 B).
__global__ void coef_kernel(const float* __restrict__ theta, float* __restrict__ coef) {
    int t = threadIdx.x;               // exactly 64 threads
    float2 th = reinterpret_cast<const float2*>(theta)[t];
    float sa = __builtin_amdgcn_sinf(th.x * INV2PI);
    float ca = __builtin_amdgcn_cosf(th.x * INV2PI);
    float sb = __builtin_amdgcn_sinf(th.y * INV2PI);
    float cb = __builtin_amdgcn_cosf(th.y * INV2PI);
    float4* c4 = reinterpret_cast<float4*>(coef);
    c4[2 * t + 0] = make_float4(cb * ca, -sb, cb * sa, sb * ca);
    c4[2 * t + 1] = make_float4(cb, sb * sa, -sa, ca);
}

__global__ __launch_bounds__(BLOCK) void sq_main(
    const float* __restrict__ x,
    const float* __restrict__ coef,
    const float* __restrict__ w,
    const float* __restrict__ bias,
    float* __restrict__ out)
{
    // Per-wave private buffer [64 rows][20 dw] = 5120 B; 4 waves = 20480 B/block
    // -> 8 blocks/CU = 32 waves/CU. No __syncthreads anywhere; single buffer is
    // race-free because same-wave DS ops execute in program order.
    __shared__ float xs[4][WSZ * STRIDE];

    const int tid  = threadIdx.x;
    const int lane = tid & 63;
    const int wid  = tid >> 6;
    const size_t wrow0 = (size_t)blockIdx.x * BLOCK + wid * 64;
    const float* xw = x + wrow0 * WSZ;
    float* ws = xs[wid];
    cfloat* cf = (cfloat*)coef;

    const float wv = w[0];
    const float bv = bias[0];

    // Coalesced staging: instr j covers rows j*16..j*16+15, 64B contiguous per row.
    const int lrow  = lane >> 2;   // 0..15
    const int lslot = lane & 3;    // float4 slot within the 16-col chunk

    float4 stage[4];
    #pragma unroll
    for (int j = 0; j < 4; ++j)
        stage[j] = *reinterpret_cast<const float4*>(
            xw + (size_t)(j * 16 + lrow) * WSZ + lslot * 4);

    float vx = 0.0f, vy = 0.0f, vz = 1.0f;

    #pragma unroll
    for (int c = 0; c < 4; ++c) {
        // store staged chunk c: 4x ds_write_b128, bank-clean via stride 20
        #pragma unroll
        for (int j = 0; j < 4; ++j)
            *reinterpret_cast<float4*>(&ws[(j * 16 + lrow) * STRIDE + lslot * 4]) = stage[j];

        // prefetch chunk c+1; flies under this chunk's compute (per-wave pipeline)
        if (c < 3) {
            #pragma unroll
            for (int j = 0; j < 4; ++j)
                stage[j] = *reinterpret_cast<const float4*>(
                    xw + (size_t)(j * 16 + lrow) * WSZ + (c + 1) * 16 + lslot * 4);
        }

        // 16 steps; lane reads its own row: ds_read_b128, conflict-free
        #pragma unroll
        for (int c2 = 0; c2 < 4; ++c2) {
            float4 xv = *reinterpret_cast<const float4*>(&ws[lane * STRIDE + c2 * 4]);
            float q[4] = {xv.x, xv.y, xv.z, xv.w};
            #pragma unroll
            for (int j = 0; j < 4; ++j) {
                const int t = c * 16 + c2 * 4 + j;   // compile-time step index
                cfloat* m = cf + t * 8;              // uniform -> s_load via K$
                float r  = q[j] * INV2PI;
                float s  = __builtin_amdgcn_sinf(r);
                float co = __builtin_amdgcn_cosf(r);
                float y1 = co * vy - s  * vz;        // Rx(x_t)
                float z1 = s  * vy + co * vz;
                float nx = m[0] * vx + m[1] * y1 + m[2] * z1;
                float ny = m[3] * vx + m[4] * y1 + m[5] * z1;
                float nz = m[6] * vx + m[7] * z1;    // m21 == 0
                vx = nx; vy = ny; vz = nz;
            }
        }
        __builtin_amdgcn_sched_barrier(0);  // bound live ranges (R7 spill lesson)
    }

    out[wrow0 + lane] = vz * wv + bv;
}

extern "C" void kernel_launch(void* const* d_in, const int* in_sizes, int n_in,
                              void* d_out, int out_size, void* d_ws, size_t ws_size,
                              hipStream_t stream) {
    const float* x     = (const float*)d_in[0];
    const float* theta = (const float*)d_in[1];
    const float* w     = (const float*)d_in[2];
    const float* b     = (const float*)d_in[3];
    float* out  = (float*)d_out;
    float* coef = (float*)d_ws;           // 64*8*4 = 2048 B scratch

    coef_kernel<<<1, WSZ, 0, stream>>>(theta, coef);

    int nrows = out_size;                 // B = 524288 (divisible by 256)
    int grid  = nrows / BLOCK;            // 2048 blocks
    sq_main<<<grid, BLOCK, 0, stream>>>(x, coef, w, b, out);
}